// Round 14
// baseline (443.790 us; speedup 1.0000x reference)
//
#include <hip/hip_runtime.h>
#include <cstdint>
#include <cstddef>

typedef __attribute__((ext_vector_type(4))) float f32x4;
typedef __attribute__((ext_vector_type(8))) short short8;

// ---------- bf16 helpers (bit-level, header-version independent) ----------
__device__ __forceinline__ unsigned short f2bf(float f) {
  unsigned int u = __float_as_uint(f);
  u += 0x7fffu + ((u >> 16) & 1u);            // round to nearest even
  return (unsigned short)(u >> 16);
}
__device__ __forceinline__ float bf2f(unsigned short h) {
  return __uint_as_float(((unsigned int)h) << 16);
}
__device__ __forceinline__ float bflo(unsigned int w) {   // low bf16 of a word
  return __uint_as_float(w << 16);
}
__device__ __forceinline__ float bfhi(unsigned int w) {   // high bf16 of a word
  return __uint_as_float(w & 0xffff0000u);
}

__device__ __forceinline__ void gload16(const unsigned short* g, unsigned short* l) {
  __builtin_amdgcn_global_load_lds(
      (const __attribute__((address_space(1))) void*)g,
      (__attribute__((address_space(3))) void*)l, 16, 0, 0);
}

// ---------- merged pre-pass: cast x, transpose+interleave wf, transpose wd,
// pack biases. One launch, block-range dispatch. ----------
// wfh row layout: phi(j) = j<2048 ? 2j : 2(j-2048)+1  ->  proj col 2e = k_e,
// col 2e+1 = hx_e: scans read ONE coalesced u32 per step.
__global__ __launch_bounds__(256) void k_prep(const float* __restrict__ x,
                                              unsigned short* __restrict__ xhi,
                                              const float* __restrict__ wf,
                                              unsigned short* __restrict__ wfh,
                                              const float* __restrict__ wd,
                                              unsigned short* __restrict__ wdt,
                                              const float* __restrict__ bfv,
                                              float2* __restrict__ bfi) {
  int blk = blockIdx.x;
  if (blk < 16384) {                       // cast x f32 -> bf16
    size_t i = ((size_t)blk * 256 + threadIdx.x) * 4;
    float4 v = *(const float4*)(x + i);
    *(ushort4*)(xhi + i) = make_ushort4(f2bf(v.x), f2bf(v.y), f2bf(v.z), f2bf(v.w));
    return;
  }
  blk -= 16384;
  if (blk < 4096) {                        // wf [1024][4096] -> wfh interleaved [4096][1024]
    __shared__ float tile[32][33];
    int tx = threadIdx.x & 31, ty = threadIdx.x >> 5;
    int bx = blk & 127, by = blk >> 7;     // 128 x 32
    int c0 = bx * 32, r0 = by * 32;
#pragma unroll
    for (int i = 0; i < 4; ++i)
      tile[ty + 8 * i][tx] = wf[(size_t)(r0 + ty + 8 * i) * 4096 + (c0 + tx)];
    __syncthreads();
#pragma unroll
    for (int i = 0; i < 4; ++i) {
      int j = c0 + ty + 8 * i;             // original wf column
      int r = (j < 2048) ? (2 * j) : (2 * (j - 2048) + 1);
      wfh[(size_t)r * 1024 + (r0 + tx)] = f2bf(tile[tx][ty + 8 * i]);
    }
    return;
  }
  blk -= 4096;
  if (blk < 2048) {                        // wd [2048][1024] -> wdt [1024][2048]
    __shared__ float tile[32][33];
    int tx = threadIdx.x & 31, ty = threadIdx.x >> 5;
    int bx = blk & 31, by = blk >> 5;      // 32 x 64
    int c0 = bx * 32, r0 = by * 32;
#pragma unroll
    for (int i = 0; i < 4; ++i)
      tile[ty + 8 * i][tx] = wd[(size_t)(r0 + ty + 8 * i) * 1024 + (c0 + tx)];
    __syncthreads();
#pragma unroll
    for (int i = 0; i < 4; ++i)
      wdt[(size_t)(c0 + ty + 8 * i) * 2048 + (r0 + tx)] = f2bf(tile[tx][ty + 8 * i]);
    return;
  }
  blk -= 2048;                             // bias pack: bfi[e] = (b_f[e], b_f[2048+e])
  int i = blk * 256 + threadIdx.x;
  if (i < 2048) bfi[i] = make_float2(bfv[i], bfv[2048 + i]);
}

// ---------- GEMM: A[M][K] (bf16, k-contig), B[N][K] (bf16, k-contig) -> C[M][N]
// R14 structural change: B-fragments read DIRECTLY from global (L2-hot weight
// panels) into registers; LDS stages A only. Rationale: the R8-R11 44%-MfmaUtil
// plateau was LDS-READ-BANDWIDTH-bound — 96 ds_read_b128 (96KB) per K-tile per
// CU at 85 B/cyc (m134) = 1129 cyc of the measured 2588. B-direct removes 32KB
// of reads (-33%) and 16KB of writes; B's ~250cyc L2 latency hides under the
// A ds_read drain (compiler inserts vmcnt(2) before first MFMA: the 2 A-stage
// gloads are the only ops younger than the 4 b4 loads).
// Geometry: 256x256 tile, BK=32, 8 waves (2M x 4N, wave-tile 128x64), A-only
// 4-buffer LDS ring (4 x 16KB = 64KB), prefetch distance 3 K-tiles.
// vmcnt (A-ring certification, 2 stage-ops/tile/wave): at tile u top,
// outstanding <= A(u+1) x2 + A(u+2) x2 -> vmcnt(4) certifies A(u); tail
// rem==1 -> vmcnt(2), rem==0 -> vmcnt(0). Wait BEFORE barrier => collective.
// Stage of tile u+3 (buf (u-1)&3) issues after barrier(u) => all waves'
// tile-u-1 ds_reads already done (lgkm waits precede their MFMAs & barrier).
// A-LDS swizzle (verified, conflicts=0): phys slot p at row r holds global
// k-chunk p ^ ((r>>1)&3); linear dest + pre-swizzled global k on stage;
// fragment read applies same XOR -> lane-group lg gets global chunk lg.
// B-direct uses lg straight -> A/B share the lane->k-chunk convention.
template<bool BF16OUT>
__global__ __launch_bounds__(512, 2) void k_gemm(const unsigned short* __restrict__ A,
                                                 const unsigned short* __restrict__ B,
                                                 void* __restrict__ Cv, int M, int N, int K) {
  __shared__ unsigned short lds[32768];      // 4 bufs x 8192 shorts = 64 KB (A only)
  const int tid = threadIdx.x, wave = tid >> 6, lane = tid & 63;
  const size_t row0 = (size_t)blockIdx.x * 256;
  const size_t col0 = (size_t)blockIdx.y * 256;
  const int wr = wave >> 2, wc = wave & 3;   // 2M x 4N waves
  const int r16 = lane & 15;
  const int lg = lane >> 4;                  // k-chunk group 0..3
  const int ksw = lg ^ ((r16 >> 1) & 3);     // swizzled k-slot for A LDS reads
  const int aoff = (wr * 128 + r16) * 32 + ksw * 8;     // within 8192-short buf
  const int gchunk = (tid & 3) ^ ((tid >> 3) & 3);      // pre-swizzled stage k-chunk
  // per-lane B base: row (col0 + wc*64 + r16), k-chunk lg (16B)
  const unsigned short* Bp = B + ((col0 + (size_t)(wc * 64 + r16)) * (size_t)K) + lg * 8;

  f32x4 acc[8][4];
#pragma unroll
  for (int i = 0; i < 8; ++i)
#pragma unroll
    for (int j = 0; j < 4; ++j) acc[i][j] = (f32x4){0.f, 0.f, 0.f, 0.f};

  // stage one 8KB half (inst 0 = rows 0-127, 1 = rows 128-255) of A K-tile kt
  auto SREG = [&](int b, int inst, int kt) {
    size_t grow = row0 + (size_t)(inst * 128 + (tid >> 2));
    gload16(A + grow * (size_t)K + (size_t)(kt * 32 + gchunk * 8),
            &lds[(b << 13) + inst * 4096 + wave * 512]);
  };

  // prologue: stage A tiles 0,1,2
#pragma unroll
  for (int t = 0; t < 3; ++t) { SREG(t, 0, t); SREG(t, 1, t); }

  const int nT = K >> 5;
  for (int u = 0; u < nT; ++u) {
    const unsigned short* buf = &lds[(u & 3) << 13];
    const int sb = (u + 3) & 3;
    const bool pf = (u + 3 < nT);
    const int rem = nT - 1 - u;
    if (rem >= 2)      asm volatile("s_waitcnt vmcnt(4)" ::: "memory");
    else if (rem == 1) asm volatile("s_waitcnt vmcnt(2)" ::: "memory");
    else               asm volatile("s_waitcnt vmcnt(0)" ::: "memory");
    asm volatile("s_barrier" ::: "memory");
    // B fragments: direct global -> register (L2-hot panel; latency hides
    // under the A ds_read drain below; compiler orders the wait)
    short8 b4[4];
#pragma unroll
    for (int nb = 0; nb < 4; ++nb)
      b4[nb] = *(const short8*)(Bp + (size_t)(nb * 16) * (size_t)K + u * 32);
    // A prefetch for tile u+3 (vm queue)
    if (pf) { SREG(sb, 0, u + 3); SREG(sb, 1, u + 3); }
    // half 1: A rows wr*128 + 0..63
    short8 a4[4];
#pragma unroll
    for (int mb = 0; mb < 4; ++mb)
      a4[mb] = *(const short8*)&buf[aoff + mb * 512];
    __builtin_amdgcn_s_setprio(1);
#pragma unroll
    for (int mb = 0; mb < 4; ++mb)
#pragma unroll
      for (int nb = 0; nb < 4; ++nb)
        acc[mb][nb] = __builtin_amdgcn_mfma_f32_16x16x32_bf16(a4[mb], b4[nb], acc[mb][nb], 0, 0, 0);
    __builtin_amdgcn_s_setprio(0);
    // half 2: A rows wr*128 + 64..127
#pragma unroll
    for (int mb = 0; mb < 4; ++mb)
      a4[mb] = *(const short8*)&buf[aoff + (4 + mb) * 512];
    __builtin_amdgcn_s_setprio(1);
#pragma unroll
    for (int mb = 0; mb < 4; ++mb)
#pragma unroll
      for (int nb = 0; nb < 4; ++nb)
        acc[4 + mb][nb] = __builtin_amdgcn_mfma_f32_16x16x32_bf16(a4[mb], b4[nb], acc[4 + mb][nb], 0, 0, 0);
    __builtin_amdgcn_s_setprio(0);
  }

  // C/D layout (HW-verified): col = lane&15, row = (lane>>4)*4 + reg
#pragma unroll
  for (int m = 0; m < 8; ++m)
#pragma unroll
    for (int n = 0; n < 4; ++n) {
      size_t row = row0 + wr * 128 + m * 16 + (lane >> 4) * 4;
      size_t col = col0 + wc * 64 + n * 16 + r16;
      if (BF16OUT) {
        unsigned short* C = (unsigned short*)Cv;
#pragma unroll
        for (int r = 0; r < 4; ++r) C[(row + r) * (size_t)N + col] = f2bf(acc[m][n][r]);
      } else {
        float* C = (float*)Cv;
#pragma unroll
        for (int r = 0; r < 4; ++r) C[(row + r) * (size_t)N + col] = acc[m][n][r];
      }
    }
}

// ---------- scan constants ----------
#define SB 4
#define ST 4096
#define SE 2048
#define CHUNK 64
#define NCHUNK 64
#define NCHAIN (SB * SE)  // 8192

// LINEAR-SPACE scan: h_t = c*h_{t-1} + v, c = sigmoid(-k), v = sigmoid(k)*g(hx).
// All positive, h in [~1e-7, ~150] — f32-safe. Cancellation-free c.
// proj INTERLEAVED: word e of a row = (k_e lo, hx_e hi).
__device__ __forceinline__ void transform_lin(float k, float hx, float& c, float& v) {
  float e = __expf(-k);
  float r = __builtin_amdgcn_rcpf(1.f + e);    // sigmoid(k)
  c = e * r;                                   // sigmoid(-k), no cancellation
  float e2 = __expf(-hx);
  float sg = __builtin_amdgcn_rcpf(1.f + e2);  // sigmoid(hx)
  float g = (hx >= 0.f) ? (hx + 0.5f) : sg;    // g(hx)
  v = r * g;
}

// K2: transforms + chunk-local linear scan (from 0) -> chunk summaries
__global__ __launch_bounds__(256) void k_scan1(const unsigned int* __restrict__ proj32,
                                               const float2* __restrict__ bfi,
                                               float* __restrict__ Ac,
                                               float* __restrict__ Bc) {
  int idx = blockIdx.x * 256 + threadIdx.x;  // (c, b, e) with e fastest
  int e = idx & (SE - 1), b = (idx >> 11) & 3, c = idx >> 13;
  const float2 bb = bfi[e];
  float A = 1.f, S = 0.f;
  size_t base = ((size_t)(b * ST + c * CHUNK)) * SE + e;
  for (int i = 0; i < CHUNK; ++i) {
    unsigned int w = proj32[base];
    float cc, vv;
    transform_lin(bflo(w) + bb.x, bfhi(w) + bb.y, cc, vv);
    A *= cc;
    S = fmaf(cc, S, vv);
    base += SE;
  }
  int chain = b * SE + e;
  Ac[(size_t)c * NCHAIN + chain] = A;
  Bc[(size_t)c * NCHAIN + chain] = S;
}

// K3: scan over chunk summaries: H_{c+1} = A_c*H_c + B_c; H_0 = exp(lh0)
__global__ __launch_bounds__(256) void k_scan2(const float* __restrict__ lh0,
                                               const float* __restrict__ Ac,
                                               const float* __restrict__ Bc,
                                               float* __restrict__ Hin) {
  int chain = blockIdx.x * 256 + threadIdx.x;  // 8192 = b*E + e
  float H = __expf(lh0[chain]);
  for (int c = 0; c < NCHUNK; ++c) {
    Hin[(size_t)c * NCHAIN + chain] = H;
    H = fmaf(Ac[(size_t)c * NCHAIN + chain], H, Bc[(size_t)c * NCHAIN + chain]);
  }
}

// K4: replay linear scan; emit h_t (bf16) and out2 = log(h) slices
__global__ __launch_bounds__(256) void k_scan3(const unsigned int* __restrict__ proj32,
                                               const float2* __restrict__ bfi,
                                               const float* __restrict__ Hin,
                                               unsigned short* __restrict__ ht,
                                               float* __restrict__ out2) {
  int idx = blockIdx.x * 256 + threadIdx.x;
  int e = idx & (SE - 1), b = (idx >> 11) & 3, c = idx >> 13;
  const float2 bb = bfi[e];
  float S = Hin[(size_t)c * NCHAIN + b * SE + e];
  size_t base = ((size_t)(b * ST + c * CHUNK)) * SE + e;
  int t = c * CHUNK;
  size_t hto = ((size_t)(b * ST + t)) * SE + e;
  for (int i = 0; i < CHUNK; ++i, ++t) {
    unsigned int w = proj32[base];
    float cc, vv;
    transform_lin(bflo(w) + bb.x, bfhi(w) + bb.y, cc, vv);
    S = fmaf(cc, S, vv);
    ht[hto] = f2bf(S);
    if (t >= 2 && ((t - 2) % 3) == 0) {   // t in {2,5,...,4094}
      int j = (t - 2) / 3;
      out2[((size_t)b * 1365 + j) * SE + e] = __logf(S);
    }
    base += SE;
    hto += SE;
  }
}

// ---------- launch ----------
extern "C" void kernel_launch(void* const* d_in, const int* in_sizes, int n_in,
                              void* d_out, int out_size, void* d_ws, size_t ws_size,
                              hipStream_t stream) {
  const float* x   = (const float*)d_in[0];
  const float* lh0 = (const float*)d_in[1];
  const float* wf  = (const float*)d_in[2];
  const float* bfv = (const float*)d_in[3];
  const float* wd  = (const float*)d_in[4];
  float* out1 = (float*)d_out;
  float* out2 = out1 + (size_t)SB * ST * 1024;

  char* p = (char*)d_ws;
  unsigned short* proj = (unsigned short*)p; p += 16384ull * 4096 * 2;  // 134 MB bf16
  unsigned short* xhi  = (unsigned short*)p; p += 16384ull * 1024 * 2;
  unsigned short* wfh  = (unsigned short*)p; p += 4096ull * 1024 * 2;
  unsigned short* wdt  = (unsigned short*)p; p += 1024ull * 2048 * 2;
  unsigned short* ht   = (unsigned short*)p; p += 16384ull * 2048 * 2;  // 67 MB
  float* Ac            = (float*)p;          p += 64ull * 8192 * 4;
  float* Bc            = (float*)p;          p += 64ull * 8192 * 4;
  float* Hin           = (float*)p;          p += 64ull * 8192 * 4;
  float2* bfi          = (float2*)p;         p += 2048ull * 8;

  // merged pre-pass
  hipLaunchKernelGGL(k_prep, dim3(16384 + 4096 + 2048 + 8), dim3(256), 0, stream,
                     x, xhi, wf, wfh, wd, wdt, bfv, bfi);
  // GEMM1 (bf16 in/out): proj = x @ w_f (cols interleaved via wfh row perm)
  hipLaunchKernelGGL((k_gemm<true>), dim3(64, 16), dim3(512), 0, stream,
                     xhi, wfh, (void*)proj, 16384, 4096, 1024);
  // 3-pass chunked LINEAR-space scan (proj read-only, word-coalesced)
  hipLaunchKernelGGL(k_scan1, dim3(2048), dim3(256), 0, stream,
                     (const unsigned int*)proj, bfi, Ac, Bc);
  hipLaunchKernelGGL(k_scan2, dim3(32), dim3(256), 0, stream, lh0, Ac, Bc, Hin);
  hipLaunchKernelGGL(k_scan3, dim3(2048), dim3(256), 0, stream,
                     (const unsigned int*)proj, bfi, Hin, ht, out2);
  // GEMM2 (bf16 in, f32 out): out1 = h_t @ w_down
  hipLaunchKernelGGL((k_gemm<false>), dim3(64, 4), dim3(512), 0, stream,
                     ht, wdt, (void*)out1, 16384, 1024, 2048);
}

// Round 15
// 314.231 us; speedup vs baseline: 1.4123x; 1.4123x over previous
//
#include <hip/hip_runtime.h>
#include <cstdint>
#include <cstddef>

typedef __attribute__((ext_vector_type(4))) float f32x4;
typedef __attribute__((ext_vector_type(8))) short short8;

// ---------- bf16 helpers (bit-level, header-version independent) ----------
__device__ __forceinline__ unsigned short f2bf(float f) {
  unsigned int u = __float_as_uint(f);
  u += 0x7fffu + ((u >> 16) & 1u);            // round to nearest even
  return (unsigned short)(u >> 16);
}
__device__ __forceinline__ float bf2f(unsigned short h) {
  return __uint_as_float(((unsigned int)h) << 16);
}
__device__ __forceinline__ float bflo(unsigned int w) {   // low bf16 of a word
  return __uint_as_float(w << 16);
}
__device__ __forceinline__ float bfhi(unsigned int w) {   // high bf16 of a word
  return __uint_as_float(w & 0xffff0000u);
}

__device__ __forceinline__ void gload16(const unsigned short* g, unsigned short* l) {
  __builtin_amdgcn_global_load_lds(
      (const __attribute__((address_space(1))) void*)g,
      (__attribute__((address_space(3))) void*)l, 16, 0, 0);
}

// ---------- merged pre-pass: cast x, transpose+interleave wf, transpose wd,
// pack biases. One launch, block-range dispatch. ----------
// wfh row layout: phi(j) = j<2048 ? 2j : 2(j-2048)+1  ->  proj col 2e = k_e,
// col 2e+1 = hx_e: scans read ONE coalesced u32 per step.
__global__ __launch_bounds__(256) void k_prep(const float* __restrict__ x,
                                              unsigned short* __restrict__ xhi,
                                              const float* __restrict__ wf,
                                              unsigned short* __restrict__ wfh,
                                              const float* __restrict__ wd,
                                              unsigned short* __restrict__ wdt,
                                              const float* __restrict__ bfv,
                                              float2* __restrict__ bfi) {
  int blk = blockIdx.x;
  if (blk < 16384) {                       // cast x f32 -> bf16
    size_t i = ((size_t)blk * 256 + threadIdx.x) * 4;
    float4 v = *(const float4*)(x + i);
    *(ushort4*)(xhi + i) = make_ushort4(f2bf(v.x), f2bf(v.y), f2bf(v.z), f2bf(v.w));
    return;
  }
  blk -= 16384;
  if (blk < 4096) {                        // wf [1024][4096] -> wfh interleaved [4096][1024]
    __shared__ float tile[32][33];
    int tx = threadIdx.x & 31, ty = threadIdx.x >> 5;
    int bx = blk & 127, by = blk >> 7;     // 128 x 32
    int c0 = bx * 32, r0 = by * 32;
#pragma unroll
    for (int i = 0; i < 4; ++i)
      tile[ty + 8 * i][tx] = wf[(size_t)(r0 + ty + 8 * i) * 4096 + (c0 + tx)];
    __syncthreads();
#pragma unroll
    for (int i = 0; i < 4; ++i) {
      int j = c0 + ty + 8 * i;             // original wf column
      int r = (j < 2048) ? (2 * j) : (2 * (j - 2048) + 1);
      wfh[(size_t)r * 1024 + (r0 + tx)] = f2bf(tile[tx][ty + 8 * i]);
    }
    return;
  }
  blk -= 4096;
  if (blk < 2048) {                        // wd [2048][1024] -> wdt [1024][2048]
    __shared__ float tile[32][33];
    int tx = threadIdx.x & 31, ty = threadIdx.x >> 5;
    int bx = blk & 31, by = blk >> 5;      // 32 x 64
    int c0 = bx * 32, r0 = by * 32;
#pragma unroll
    for (int i = 0; i < 4; ++i)
      tile[ty + 8 * i][tx] = wd[(size_t)(r0 + ty + 8 * i) * 1024 + (c0 + tx)];
    __syncthreads();
#pragma unroll
    for (int i = 0; i < 4; ++i)
      wdt[(size_t)(c0 + ty + 8 * i) * 2048 + (r0 + tx)] = f2bf(tile[tx][ty + 8 * i]);
    return;
  }
  blk -= 2048;                             // bias pack: bfi[e] = (b_f[e], b_f[2048+e])
  int i = blk * 256 + threadIdx.x;
  if (i < 2048) bfi[i] = make_float2(bfv[i], bfv[2048 + i]);
}

// ---------- GEMM: A[M][K] (bf16, k-contig), B[N][K] (bf16, k-contig) -> C[M][N]
// R15: R13's proven ring (256x256 tile, BK=32, 8 waves 2Mx4N, 4-buffer LDS ring,
// distance-3 stage, verified swizzle) with fragment reads ROTATED one K-tile
// early. Diagnosis: R8-R13's 44% MfmaUtil = LDS-read (1152cyc) and MFMA
// (1242cyc) running SERIALLY per K-tile — every read consumed in the same
// iteration it was issued, so each MFMA cluster stalls on a fresh lgkm wait.
// New schedule per iter u:
//   - a2 reads: tile u's A-half2 from buf u (certified at iter u-1) — issued
//     at iter top, consumed by cluster 2 (latency hides under cluster 1)
//   - vmcnt(4): certify buffer u+1 (staged at iter u-2; outstanding = tiles
//     u+1,u+2 = 8 loads, oldest-first m135) ; tail: vmcnt(0) when u+2>=nT
//   - barrier ; stage tile u+3 into buf (u-1)&3
//   - bn/a1n reads: tile u+1's B + A-half1 into the OTHER frag set
//   - cluster 1 MFMA on bc/a1c (read LAST iter -> no lgkm dependency)
//   - cluster 2 MFMA on a2/bc
// All lgkm waits now target reads issued >=1 iteration (~2000cyc) earlier;
// the LDS pipe drains DURING MFMA execution.
// Race-freedom: reads of buf (u-1) (a2 at iter u-1, bn/a1n at iter u-2) are
// consumed by MFMA before their wave reaches barrier(u) -> complete before
// stage(u+3) writes buf (u-1)&3 after barrier(u). Read-after-write: vmcnt at
// iter u certifies buf u+1 before its reads (per-wave cert + barrier ->
// collective). Frag double-buffer: named sets + x2 unroll (nT=32/64, even).
template<bool BF16OUT>
__global__ __launch_bounds__(512, 2) void k_gemm(const unsigned short* __restrict__ A,
                                                 const unsigned short* __restrict__ B,
                                                 void* __restrict__ Cv, int M, int N, int K) {
  __shared__ unsigned short lds[65536];      // 4 bufs x 16384 shorts = 128 KB
  const int tid = threadIdx.x, wave = tid >> 6, lane = tid & 63;
  const size_t row0 = (size_t)blockIdx.x * 256;
  const size_t col0 = (size_t)blockIdx.y * 256;
  const int wr = wave >> 2, wc = wave & 3;   // 2M x 4N waves
  const int r16 = lane & 15;
  const int ksw = (lane >> 4) ^ ((r16 >> 1) & 3);       // swizzled k-slot (0..3)
  const int aoff = (wr * 128 + r16) * 32 + ksw * 8;     // A region: shorts 0..8191
  const int boff = 8192 + (wc * 64 + r16) * 32 + ksw * 8;
  const int gchunk = (tid & 3) ^ ((tid >> 3) & 3);      // pre-swizzled global k-chunk

  f32x4 acc[8][4];
#pragma unroll
  for (int i = 0; i < 8; ++i)
#pragma unroll
    for (int j = 0; j < 4; ++j) acc[i][j] = (f32x4){0.f, 0.f, 0.f, 0.f};

  auto SREG = [&](int b, int arr, int inst, int kt) {
    const unsigned short* src = arr ? B : A;
    size_t grow = (arr ? col0 : row0) + (size_t)(inst * 128 + (tid >> 2));
    gload16(src + grow * (size_t)K + (size_t)(kt * 32 + gchunk * 8),
            &lds[(b << 14) + arr * 8192 + inst * 4096 + wave * 512]);
  };

  // prologue: stage tiles 0,1,2 into bufs 0,1,2; certify tile 0; pre-read set A
#pragma unroll
  for (int t = 0; t < 3; ++t) {
    SREG(t, 0, 0, t); SREG(t, 0, 1, t);
    SREG(t, 1, 0, t); SREG(t, 1, 1, t);
  }
  const int nT = K >> 5;
  asm volatile("s_waitcnt vmcnt(8)" ::: "memory");
  asm volatile("s_barrier" ::: "memory");

  short8 bA[4], a1A[4], bB[4], a1B[4];
#pragma unroll
  for (int nb = 0; nb < 4; ++nb) bA[nb] = *(const short8*)&lds[boff + nb * 512];
#pragma unroll
  for (int mb = 0; mb < 4; ++mb) a1A[mb] = *(const short8*)&lds[aoff + mb * 512];

  auto ITER = [&](int u, short8 (&bc)[4], short8 (&a1c)[4],
                  short8 (&bn)[4], short8 (&a1n)[4]) {
    const unsigned short* buf = &lds[(u & 3) << 14];
    // tile u's A-half2 (buffer certified last iter): issue early, consumed by cluster 2
    short8 a2[4];
#pragma unroll
    for (int mb = 0; mb < 4; ++mb)
      a2[mb] = *(const short8*)&buf[aoff + (4 + mb) * 512];
    if (u + 1 < nT) {
      if (u + 2 < nT) asm volatile("s_waitcnt vmcnt(4)" ::: "memory");
      else            asm volatile("s_waitcnt vmcnt(0)" ::: "memory");
      asm volatile("s_barrier" ::: "memory");
      if (u + 3 < nT) {
        const int sb = (u + 3) & 3;
        SREG(sb, 0, 0, u + 3); SREG(sb, 0, 1, u + 3);
        SREG(sb, 1, 0, u + 3); SREG(sb, 1, 1, u + 3);
      }
      const unsigned short* nbf = &lds[((u + 1) & 3) << 14];
#pragma unroll
      for (int nb = 0; nb < 4; ++nb) bn[nb] = *(const short8*)&nbf[boff + nb * 512];
#pragma unroll
      for (int mb = 0; mb < 4; ++mb) a1n[mb] = *(const short8*)&nbf[aoff + mb * 512];
    }
    // cluster 1: operands read LAST iteration — no fresh lgkm dependency
    __builtin_amdgcn_s_setprio(1);
#pragma unroll
    for (int mb = 0; mb < 4; ++mb)
#pragma unroll
      for (int nb = 0; nb < 4; ++nb)
        acc[mb][nb] = __builtin_amdgcn_mfma_f32_16x16x32_bf16(a1c[mb], bc[nb], acc[mb][nb], 0, 0, 0);
    __builtin_amdgcn_s_setprio(0);
    // cluster 2: a2 (issued at iter top — latency hidden under cluster 1)
    __builtin_amdgcn_s_setprio(1);
#pragma unroll
    for (int mb = 0; mb < 4; ++mb)
#pragma unroll
      for (int nb = 0; nb < 4; ++nb)
        acc[4 + mb][nb] = __builtin_amdgcn_mfma_f32_16x16x32_bf16(a2[mb], bc[nb], acc[4 + mb][nb], 0, 0, 0);
    __builtin_amdgcn_s_setprio(0);
  };

  for (int u = 0; u < nT; u += 2) {
    ITER(u, bA, a1A, bB, a1B);
    ITER(u + 1, bB, a1B, bA, a1A);
  }

  // C/D layout (HW-verified): col = lane&15, row = (lane>>4)*4 + reg
#pragma unroll
  for (int m = 0; m < 8; ++m)
#pragma unroll
    for (int n = 0; n < 4; ++n) {
      size_t row = row0 + wr * 128 + m * 16 + (lane >> 4) * 4;
      size_t col = col0 + wc * 64 + n * 16 + r16;
      if (BF16OUT) {
        unsigned short* C = (unsigned short*)Cv;
#pragma unroll
        for (int r = 0; r < 4; ++r) C[(row + r) * (size_t)N + col] = f2bf(acc[m][n][r]);
      } else {
        float* C = (float*)Cv;
#pragma unroll
        for (int r = 0; r < 4; ++r) C[(row + r) * (size_t)N + col] = acc[m][n][r];
      }
    }
}

// ---------- scan constants ----------
#define SB 4
#define ST 4096
#define SE 2048
#define CHUNK 64
#define NCHUNK 64
#define NCHAIN (SB * SE)  // 8192

// LINEAR-SPACE scan: h_t = c*h_{t-1} + v, c = sigmoid(-k), v = sigmoid(k)*g(hx).
// All positive, h in [~1e-7, ~150] — f32-safe. Cancellation-free c.
// proj INTERLEAVED: word e of a row = (k_e lo, hx_e hi).
__device__ __forceinline__ void transform_lin(float k, float hx, float& c, float& v) {
  float e = __expf(-k);
  float r = __builtin_amdgcn_rcpf(1.f + e);    // sigmoid(k)
  c = e * r;                                   // sigmoid(-k), no cancellation
  float e2 = __expf(-hx);
  float sg = __builtin_amdgcn_rcpf(1.f + e2);  // sigmoid(hx)
  float g = (hx >= 0.f) ? (hx + 0.5f) : sg;    // g(hx)
  v = r * g;
}

// K2: transforms + chunk-local linear scan (from 0) -> chunk summaries
__global__ __launch_bounds__(256) void k_scan1(const unsigned int* __restrict__ proj32,
                                               const float2* __restrict__ bfi,
                                               float* __restrict__ Ac,
                                               float* __restrict__ Bc) {
  int idx = blockIdx.x * 256 + threadIdx.x;  // (c, b, e) with e fastest
  int e = idx & (SE - 1), b = (idx >> 11) & 3, c = idx >> 13;
  const float2 bb = bfi[e];
  float A = 1.f, S = 0.f;
  size_t base = ((size_t)(b * ST + c * CHUNK)) * SE + e;
  for (int i = 0; i < CHUNK; ++i) {
    unsigned int w = proj32[base];
    float cc, vv;
    transform_lin(bflo(w) + bb.x, bfhi(w) + bb.y, cc, vv);
    A *= cc;
    S = fmaf(cc, S, vv);
    base += SE;
  }
  int chain = b * SE + e;
  Ac[(size_t)c * NCHAIN + chain] = A;
  Bc[(size_t)c * NCHAIN + chain] = S;
}

// K3: scan over chunk summaries: H_{c+1} = A_c*H_c + B_c; H_0 = exp(lh0)
__global__ __launch_bounds__(256) void k_scan2(const float* __restrict__ lh0,
                                               const float* __restrict__ Ac,
                                               const float* __restrict__ Bc,
                                               float* __restrict__ Hin) {
  int chain = blockIdx.x * 256 + threadIdx.x;  // 8192 = b*E + e
  float H = __expf(lh0[chain]);
  for (int c = 0; c < NCHUNK; ++c) {
    Hin[(size_t)c * NCHAIN + chain] = H;
    H = fmaf(Ac[(size_t)c * NCHAIN + chain], H, Bc[(size_t)c * NCHAIN + chain]);
  }
}

// K4: replay linear scan; emit h_t (bf16) and out2 = log(h) slices
__global__ __launch_bounds__(256) void k_scan3(const unsigned int* __restrict__ proj32,
                                               const float2* __restrict__ bfi,
                                               const float* __restrict__ Hin,
                                               unsigned short* __restrict__ ht,
                                               float* __restrict__ out2) {
  int idx = blockIdx.x * 256 + threadIdx.x;
  int e = idx & (SE - 1), b = (idx >> 11) & 3, c = idx >> 13;
  const float2 bb = bfi[e];
  float S = Hin[(size_t)c * NCHAIN + b * SE + e];
  size_t base = ((size_t)(b * ST + c * CHUNK)) * SE + e;
  int t = c * CHUNK;
  size_t hto = ((size_t)(b * ST + t)) * SE + e;
  for (int i = 0; i < CHUNK; ++i, ++t) {
    unsigned int w = proj32[base];
    float cc, vv;
    transform_lin(bflo(w) + bb.x, bfhi(w) + bb.y, cc, vv);
    S = fmaf(cc, S, vv);
    ht[hto] = f2bf(S);
    if (t >= 2 && ((t - 2) % 3) == 0) {   // t in {2,5,...,4094}
      int j = (t - 2) / 3;
      out2[((size_t)b * 1365 + j) * SE + e] = __logf(S);
    }
    base += SE;
    hto += SE;
  }
}

// ---------- launch ----------
extern "C" void kernel_launch(void* const* d_in, const int* in_sizes, int n_in,
                              void* d_out, int out_size, void* d_ws, size_t ws_size,
                              hipStream_t stream) {
  const float* x   = (const float*)d_in[0];
  const float* lh0 = (const float*)d_in[1];
  const float* wf  = (const float*)d_in[2];
  const float* bfv = (const float*)d_in[3];
  const float* wd  = (const float*)d_in[4];
  float* out1 = (float*)d_out;
  float* out2 = out1 + (size_t)SB * ST * 1024;

  char* p = (char*)d_ws;
  unsigned short* proj = (unsigned short*)p; p += 16384ull * 4096 * 2;  // 134 MB bf16
  unsigned short* xhi  = (unsigned short*)p; p += 16384ull * 1024 * 2;
  unsigned short* wfh  = (unsigned short*)p; p += 4096ull * 1024 * 2;
  unsigned short* wdt  = (unsigned short*)p; p += 1024ull * 2048 * 2;
  unsigned short* ht   = (unsigned short*)p; p += 16384ull * 2048 * 2;  // 67 MB
  float* Ac            = (float*)p;          p += 64ull * 8192 * 4;
  float* Bc            = (float*)p;          p += 64ull * 8192 * 4;
  float* Hin           = (float*)p;          p += 64ull * 8192 * 4;
  float2* bfi          = (float2*)p;         p += 2048ull * 8;

  // merged pre-pass
  hipLaunchKernelGGL(k_prep, dim3(16384 + 4096 + 2048 + 8), dim3(256), 0, stream,
                     x, xhi, wf, wfh, wd, wdt, bfv, bfi);
  // GEMM1 (bf16 in/out): proj = x @ w_f (cols interleaved via wfh row perm)
  hipLaunchKernelGGL((k_gemm<true>), dim3(64, 16), dim3(512), 0, stream,
                     xhi, wfh, (void*)proj, 16384, 4096, 1024);
  // 3-pass chunked LINEAR-space scan (proj read-only, word-coalesced)
  hipLaunchKernelGGL(k_scan1, dim3(2048), dim3(256), 0, stream,
                     (const unsigned int*)proj, bfi, Ac, Bc);
  hipLaunchKernelGGL(k_scan2, dim3(32), dim3(256), 0, stream, lh0, Ac, Bc, Hin);
  hipLaunchKernelGGL(k_scan3, dim3(2048), dim3(256), 0, stream,
                     (const unsigned int*)proj, bfi, Hin, ht, out2);
  // GEMM2 (bf16 in, f32 out): out1 = h_t @ w_down
  hipLaunchKernelGGL((k_gemm<false>), dim3(64, 4), dim3(512), 0, stream,
                     ht, wdt, (void*)out1, 16384, 1024, 2048);
}

// Round 16
// 300.821 us; speedup vs baseline: 1.4753x; 1.0446x over previous
//
#include <hip/hip_runtime.h>
#include <cstdint>
#include <cstddef>

typedef __attribute__((ext_vector_type(4))) float f32x4;
typedef __attribute__((ext_vector_type(8))) short short8;

// ---------- bf16 helpers (bit-level, header-version independent) ----------
__device__ __forceinline__ unsigned short f2bf(float f) {
  unsigned int u = __float_as_uint(f);
  u += 0x7fffu + ((u >> 16) & 1u);            // round to nearest even
  return (unsigned short)(u >> 16);
}
__device__ __forceinline__ float bf2f(unsigned short h) {
  return __uint_as_float(((unsigned int)h) << 16);
}
__device__ __forceinline__ float bflo(unsigned int w) {   // low bf16 of a word
  return __uint_as_float(w << 16);
}
__device__ __forceinline__ float bfhi(unsigned int w) {   // high bf16 of a word
  return __uint_as_float(w & 0xffff0000u);
}

__device__ __forceinline__ void gload16(const unsigned short* g, unsigned short* l) {
  __builtin_amdgcn_global_load_lds(
      (const __attribute__((address_space(1))) void*)g,
      (__attribute__((address_space(3))) void*)l, 16, 0, 0);
}

// ---------- merged pre-pass: cast x, transpose+interleave wf, transpose wd,
// pack biases. One launch, block-range dispatch. ----------
// wfh row layout: phi(j) = j<2048 ? 2j : 2(j-2048)+1  ->  proj col 2e = k_e,
// col 2e+1 = hx_e: scans read ONE coalesced u32 per step.
__global__ __launch_bounds__(256) void k_prep(const float* __restrict__ x,
                                              unsigned short* __restrict__ xhi,
                                              const float* __restrict__ wf,
                                              unsigned short* __restrict__ wfh,
                                              const float* __restrict__ wd,
                                              unsigned short* __restrict__ wdt,
                                              const float* __restrict__ bfv,
                                              float2* __restrict__ bfi) {
  int blk = blockIdx.x;
  if (blk < 16384) {                       // cast x f32 -> bf16
    size_t i = ((size_t)blk * 256 + threadIdx.x) * 4;
    float4 v = *(const float4*)(x + i);
    *(ushort4*)(xhi + i) = make_ushort4(f2bf(v.x), f2bf(v.y), f2bf(v.z), f2bf(v.w));
    return;
  }
  blk -= 16384;
  if (blk < 4096) {                        // wf [1024][4096] -> wfh interleaved [4096][1024]
    __shared__ float tile[32][33];
    int tx = threadIdx.x & 31, ty = threadIdx.x >> 5;
    int bx = blk & 127, by = blk >> 7;     // 128 x 32
    int c0 = bx * 32, r0 = by * 32;
#pragma unroll
    for (int i = 0; i < 4; ++i)
      tile[ty + 8 * i][tx] = wf[(size_t)(r0 + ty + 8 * i) * 4096 + (c0 + tx)];
    __syncthreads();
#pragma unroll
    for (int i = 0; i < 4; ++i) {
      int j = c0 + ty + 8 * i;             // original wf column
      int r = (j < 2048) ? (2 * j) : (2 * (j - 2048) + 1);
      wfh[(size_t)r * 1024 + (r0 + tx)] = f2bf(tile[tx][ty + 8 * i]);
    }
    return;
  }
  blk -= 4096;
  if (blk < 2048) {                        // wd [2048][1024] -> wdt [1024][2048]
    __shared__ float tile[32][33];
    int tx = threadIdx.x & 31, ty = threadIdx.x >> 5;
    int bx = blk & 31, by = blk >> 5;      // 32 x 64
    int c0 = bx * 32, r0 = by * 32;
#pragma unroll
    for (int i = 0; i < 4; ++i)
      tile[ty + 8 * i][tx] = wd[(size_t)(r0 + ty + 8 * i) * 1024 + (c0 + tx)];
    __syncthreads();
#pragma unroll
    for (int i = 0; i < 4; ++i)
      wdt[(size_t)(c0 + ty + 8 * i) * 2048 + (r0 + tx)] = f2bf(tile[tx][ty + 8 * i]);
    return;
  }
  blk -= 2048;                             // bias pack: bfi[e] = (b_f[e], b_f[2048+e])
  int i = blk * 256 + threadIdx.x;
  if (i < 2048) bfi[i] = make_float2(bfv[i], bfv[2048 + i]);
}

// ---------- GEMM: A[M][K] (bf16, k-contig), B[N][K] (bf16, k-contig) -> C[M][N]
// R16: R13's proven pattern with BK=64, ring-2 (2 x 64KB), distance-1 prefetch.
// Halves sync events per FLOP: ONE vmcnt(0) + ONE barrier per K-64 (R13 had
// one per K-32). The vmcnt(0) here is EXACT certification, not a drain: at the
// wait, outstanding = only tile u's 8 stage-ops issued one full tile (~5000cyc)
// earlier — tile u+1's stage not yet issued -> no pessimistic wait.
// Race-freedom: stage(u+1) -> buf (u+1)&1 issues after barrier(u); the only
// prior reads of that buffer (tile u-1's) completed before each wave's barrier
// arrival (ds_read -> lgkm-dependent MFMA -> barrier). Read-after-write: the
// top-of-iter vmcnt(0) (own loads) + barrier (collective) certify buf u.
// Per K-tile/wave: 8 stage gloads, 24 ds_read_b128, 64 MFMA in 4 clusters of
// 16 {read a4 | MFMA}, b8 (8 reads) up front. Acc order per element stays
// k-ascending (kh=0 cluster then kh=1) -> bit-identical to R13.
// LDS swizzle (8-slot generalization of the verified conflict-free family):
// row of 64 k = 8 slots of 8 shorts; phys slot p at row r holds global k-chunk
// p ^ ((r>>1)&7). Stage: linear dest, pre-swizzled global chunk
// (tid&7)^((tid>>4)&7) (row-in-region = tid>>3; region = 64-row slab).
// Read: slot = (kh*4+lg) ^ ((r16>>1)&7); consecutive row-pairs hit 8 distinct
// slots, 2 lanes each (2-way = free). A and B share the lane->k-chunk
// convention -> contraction correct independent of HW k-labeling.
template<bool BF16OUT>
__global__ __launch_bounds__(512, 2) void k_gemm(const unsigned short* __restrict__ A,
                                                 const unsigned short* __restrict__ B,
                                                 void* __restrict__ Cv, int M, int N, int K) {
  __shared__ unsigned short lds[65536];      // 2 bufs x 32768 shorts = 128 KB
  const int tid = threadIdx.x, wave = tid >> 6, lane = tid & 63;
  const size_t row0 = (size_t)blockIdx.x * 256;
  const size_t col0 = (size_t)blockIdx.y * 256;
  const int wr = wave >> 2, wc = wave & 3;   // 2M x 4N waves, wave-tile 128x64
  const int r16 = lane & 15;
  const int lg = lane >> 4;                  // lane k-group 0..3
  const int xm = (r16 >> 1) & 7;             // row swizzle mask
  const int gchunk = (tid & 7) ^ ((tid >> 4) & 7);   // stage pre-swizzled k-chunk

  f32x4 acc[8][4];
#pragma unroll
  for (int i = 0; i < 8; ++i)
#pragma unroll
    for (int j = 0; j < 4; ++j) acc[i][j] = (f32x4){0.f, 0.f, 0.f, 0.f};

  // stage one 8KB region (arr 0=A,1=B; reg = 64-row slab 0..3) of K-tile kt
  // into ring buffer b. Thread: row reg*64 + (tid>>3), 16B at slot tid&7.
  auto SREG = [&](int b, int arr, int reg, int kt) {
    const unsigned short* src = arr ? B : A;
    size_t grow = (arr ? col0 : row0) + (size_t)(reg * 64 + (tid >> 3));
    gload16(src + grow * (size_t)K + (size_t)(kt * 64 + gchunk * 8),
            &lds[(b << 15) + arr * 16384 + reg * 4096 + wave * 512]);
  };
  auto STAGE = [&](int b, int kt) {
#pragma unroll
    for (int reg = 0; reg < 4; ++reg) SREG(b, 0, reg, kt);
#pragma unroll
    for (int reg = 0; reg < 4; ++reg) SREG(b, 1, reg, kt);
  };

  // fragment offsets (shorts): row*64 + swizzled-slot*8
  auto AOFF = [&](int mb, int kh) -> int {
    int r = wr * 128 + mb * 16 + r16;
    return r * 64 + (((kh * 4 + lg) ^ xm) * 8);
  };
  auto BOFF = [&](int nb, int kh) -> int {
    int r = wc * 64 + nb * 16 + r16;
    return 16384 + r * 64 + (((kh * 4 + lg) ^ xm) * 8);
  };

  STAGE(0, 0);                               // prologue
  const int nT = K >> 6;
  for (int u = 0; u < nT; ++u) {
    const unsigned short* buf = &lds[(u & 1) << 15];
    asm volatile("s_waitcnt vmcnt(0)" ::: "memory");   // exact cert of tile u
    asm volatile("s_barrier" ::: "memory");
    if (u + 1 < nT) STAGE((u & 1) ^ 1, u + 1);         // distance-1 prefetch
    short8 b8[8];
#pragma unroll
    for (int kh = 0; kh < 2; ++kh)
#pragma unroll
      for (int nb = 0; nb < 4; ++nb)
        b8[kh * 4 + nb] = *(const short8*)&buf[BOFF(nb, kh)];
#pragma unroll
    for (int kh = 0; kh < 2; ++kh) {
      short8 a4[4];
#pragma unroll
      for (int mb = 0; mb < 4; ++mb)
        a4[mb] = *(const short8*)&buf[AOFF(mb, kh)];
      __builtin_amdgcn_s_setprio(1);
#pragma unroll
      for (int mb = 0; mb < 4; ++mb)
#pragma unroll
        for (int nb = 0; nb < 4; ++nb)
          acc[mb][nb] = __builtin_amdgcn_mfma_f32_16x16x32_bf16(a4[mb], b8[kh * 4 + nb], acc[mb][nb], 0, 0, 0);
      __builtin_amdgcn_s_setprio(0);
#pragma unroll
      for (int mb = 0; mb < 4; ++mb)
        a4[mb] = *(const short8*)&buf[AOFF(4 + mb, kh)];
      __builtin_amdgcn_s_setprio(1);
#pragma unroll
      for (int mb = 0; mb < 4; ++mb)
#pragma unroll
        for (int nb = 0; nb < 4; ++nb)
          acc[4 + mb][nb] = __builtin_amdgcn_mfma_f32_16x16x32_bf16(a4[mb], b8[kh * 4 + nb], acc[4 + mb][nb], 0, 0, 0);
      __builtin_amdgcn_s_setprio(0);
    }
  }

  // C/D layout (HW-verified): col = lane&15, row = (lane>>4)*4 + reg
#pragma unroll
  for (int m = 0; m < 8; ++m)
#pragma unroll
    for (int n = 0; n < 4; ++n) {
      size_t row = row0 + wr * 128 + m * 16 + (lane >> 4) * 4;
      size_t col = col0 + wc * 64 + n * 16 + r16;
      if (BF16OUT) {
        unsigned short* C = (unsigned short*)Cv;
#pragma unroll
        for (int r = 0; r < 4; ++r) C[(row + r) * (size_t)N + col] = f2bf(acc[m][n][r]);
      } else {
        float* C = (float*)Cv;
#pragma unroll
        for (int r = 0; r < 4; ++r) C[(row + r) * (size_t)N + col] = acc[m][n][r];
      }
    }
}

// ---------- scan constants ----------
#define SB 4
#define ST 4096
#define SE 2048
#define CHUNK 64
#define NCHUNK 64
#define NCHAIN (SB * SE)  // 8192

// LINEAR-SPACE scan: h_t = c*h_{t-1} + v, c = sigmoid(-k), v = sigmoid(k)*g(hx).
// All positive, h in [~1e-7, ~150] — f32-safe. Cancellation-free c.
// proj INTERLEAVED: word e of a row = (k_e lo, hx_e hi).
__device__ __forceinline__ void transform_lin(float k, float hx, float& c, float& v) {
  float e = __expf(-k);
  float r = __builtin_amdgcn_rcpf(1.f + e);    // sigmoid(k)
  c = e * r;                                   // sigmoid(-k), no cancellation
  float e2 = __expf(-hx);
  float sg = __builtin_amdgcn_rcpf(1.f + e2);  // sigmoid(hx)
  float g = (hx >= 0.f) ? (hx + 0.5f) : sg;    // g(hx)
  v = r * g;
}

// K2: transforms + chunk-local linear scan (from 0) -> chunk summaries
__global__ __launch_bounds__(256) void k_scan1(const unsigned int* __restrict__ proj32,
                                               const float2* __restrict__ bfi,
                                               float* __restrict__ Ac,
                                               float* __restrict__ Bc) {
  int idx = blockIdx.x * 256 + threadIdx.x;  // (c, b, e) with e fastest
  int e = idx & (SE - 1), b = (idx >> 11) & 3, c = idx >> 13;
  const float2 bb = bfi[e];
  float A = 1.f, S = 0.f;
  size_t base = ((size_t)(b * ST + c * CHUNK)) * SE + e;
  for (int i = 0; i < CHUNK; ++i) {
    unsigned int w = proj32[base];
    float cc, vv;
    transform_lin(bflo(w) + bb.x, bfhi(w) + bb.y, cc, vv);
    A *= cc;
    S = fmaf(cc, S, vv);
    base += SE;
  }
  int chain = b * SE + e;
  Ac[(size_t)c * NCHAIN + chain] = A;
  Bc[(size_t)c * NCHAIN + chain] = S;
}

// K3: scan over chunk summaries: H_{c+1} = A_c*H_c + B_c; H_0 = exp(lh0)
__global__ __launch_bounds__(256) void k_scan2(const float* __restrict__ lh0,
                                               const float* __restrict__ Ac,
                                               const float* __restrict__ Bc,
                                               float* __restrict__ Hin) {
  int chain = blockIdx.x * 256 + threadIdx.x;  // 8192 = b*E + e
  float H = __expf(lh0[chain]);
  for (int c = 0; c < NCHUNK; ++c) {
    Hin[(size_t)c * NCHAIN + chain] = H;
    H = fmaf(Ac[(size_t)c * NCHAIN + chain], H, Bc[(size_t)c * NCHAIN + chain]);
  }
}

// K4: replay linear scan; emit h_t (bf16) and out2 = log(h) slices
__global__ __launch_bounds__(256) void k_scan3(const unsigned int* __restrict__ proj32,
                                               const float2* __restrict__ bfi,
                                               const float* __restrict__ Hin,
                                               unsigned short* __restrict__ ht,
                                               float* __restrict__ out2) {
  int idx = blockIdx.x * 256 + threadIdx.x;
  int e = idx & (SE - 1), b = (idx >> 11) & 3, c = idx >> 13;
  const float2 bb = bfi[e];
  float S = Hin[(size_t)c * NCHAIN + b * SE + e];
  size_t base = ((size_t)(b * ST + c * CHUNK)) * SE + e;
  int t = c * CHUNK;
  size_t hto = ((size_t)(b * ST + t)) * SE + e;
  for (int i = 0; i < CHUNK; ++i, ++t) {
    unsigned int w = proj32[base];
    float cc, vv;
    transform_lin(bflo(w) + bb.x, bfhi(w) + bb.y, cc, vv);
    S = fmaf(cc, S, vv);
    ht[hto] = f2bf(S);
    if (t >= 2 && ((t - 2) % 3) == 0) {   // t in {2,5,...,4094}
      int j = (t - 2) / 3;
      out2[((size_t)b * 1365 + j) * SE + e] = __logf(S);
    }
    base += SE;
    hto += SE;
  }
}

// ---------- launch ----------
extern "C" void kernel_launch(void* const* d_in, const int* in_sizes, int n_in,
                              void* d_out, int out_size, void* d_ws, size_t ws_size,
                              hipStream_t stream) {
  const float* x   = (const float*)d_in[0];
  const float* lh0 = (const float*)d_in[1];
  const float* wf  = (const float*)d_in[2];
  const float* bfv = (const float*)d_in[3];
  const float* wd  = (const float*)d_in[4];
  float* out1 = (float*)d_out;
  float* out2 = out1 + (size_t)SB * ST * 1024;

  char* p = (char*)d_ws;
  unsigned short* proj = (unsigned short*)p; p += 16384ull * 4096 * 2;  // 134 MB bf16
  unsigned short* xhi  = (unsigned short*)p; p += 16384ull * 1024 * 2;
  unsigned short* wfh  = (unsigned short*)p; p += 4096ull * 1024 * 2;
  unsigned short* wdt  = (unsigned short*)p; p += 1024ull * 2048 * 2;
  unsigned short* ht   = (unsigned short*)p; p += 16384ull * 2048 * 2;  // 67 MB
  float* Ac            = (float*)p;          p += 64ull * 8192 * 4;
  float* Bc            = (float*)p;          p += 64ull * 8192 * 4;
  float* Hin           = (float*)p;          p += 64ull * 8192 * 4;
  float2* bfi          = (float2*)p;         p += 2048ull * 8;

  // merged pre-pass
  hipLaunchKernelGGL(k_prep, dim3(16384 + 4096 + 2048 + 8), dim3(256), 0, stream,
                     x, xhi, wf, wfh, wd, wdt, bfv, bfi);
  // GEMM1 (bf16 in/out): proj = x @ w_f (cols interleaved via wfh row perm)
  hipLaunchKernelGGL((k_gemm<true>), dim3(64, 16), dim3(512), 0, stream,
                     xhi, wfh, (void*)proj, 16384, 4096, 1024);
  // 3-pass chunked LINEAR-space scan (proj read-only, word-coalesced)
  hipLaunchKernelGGL(k_scan1, dim3(2048), dim3(256), 0, stream,
                     (const unsigned int*)proj, bfi, Ac, Bc);
  hipLaunchKernelGGL(k_scan2, dim3(32), dim3(256), 0, stream, lh0, Ac, Bc, Hin);
  hipLaunchKernelGGL(k_scan3, dim3(2048), dim3(256), 0, stream,
                     (const unsigned int*)proj, bfi, Hin, ht, out2);
  // GEMM2 (bf16 in, f32 out): out1 = h_t @ w_down
  hipLaunchKernelGGL((k_gemm<false>), dim3(64, 4), dim3(512), 0, stream,
                     ht, wdt, (void*)out1, 16384, 1024, 2048);
}